// Round 11
// baseline (698.499 us; speedup 1.0000x reference)
//
#include <hip/hip_runtime.h>
#include <stdint.h>

#define IN_F 4096
#define OUT_F 4096
#define M_TOT 8192
#define LORA_SCALE 4.0f   // ALPHA / RANK = 32 / 8

typedef unsigned short u16;
typedef __attribute__((ext_vector_type(8))) short bf16x8;   // 8 bf16 = 4 VGPRs
typedef __attribute__((ext_vector_type(4))) float f32x4;

__device__ __forceinline__ u16 f2bf(float f) {
  union { float f; unsigned u; } v; v.f = f;
  unsigned r = v.u + 0x7FFFu + ((v.u >> 16) & 1u);  // round-to-nearest-even
  return (u16)(r >> 16);
}

__device__ __forceinline__ void gload_lds16(const void* g, void* l) {
  __builtin_amdgcn_global_load_lds(
      (const __attribute__((address_space(1))) void*)g,
      (__attribute__((address_space(3))) void*)l, 16, 0, 0);
}

// ---------------------------------------------------------------------------
// Prep (Wb only now): Wb[o][i] = bf16( W[o][i] + 4 * sum_r a[o][r]*b[r][i] )
__global__ void prep_w(const float* __restrict__ W, const float* __restrict__ A,
                       const float* __restrict__ B, u16* __restrict__ Wb) {
  int idx = blockIdx.x * blockDim.x + threadIdx.x;
  int o  = idx >> 10;
  int i0 = (idx & 1023) << 2;
  const f32x4 w = __builtin_nontemporal_load((const f32x4*)(W + (size_t)o * IN_F + i0));
  float a0 = w.x, a1 = w.y, a2 = w.z, a3 = w.w;
#pragma unroll
  for (int r = 0; r < 8; ++r) {
    float ar = A[o * 8 + r] * LORA_SCALE;
    const float4 bv = *(const float4*)(B + (size_t)r * IN_F + i0);
    a0 += ar * bv.x; a1 += ar * bv.y; a2 += ar * bv.z; a3 += ar * bv.w;
  }
  uint2 pk;
  pk.x = (unsigned)f2bf(a0) | ((unsigned)f2bf(a1) << 16);
  pk.y = (unsigned)f2bf(a2) | ((unsigned)f2bf(a3) << 16);
  *(uint2*)(Wb + (size_t)o * IN_F + i0) = pk;
}

// Fallback-path X conversion (only used if gemm8 can't launch)
__global__ void convert_x(const float* __restrict__ X, u16* __restrict__ Xb) {
  size_t base = ((size_t)blockIdx.x * blockDim.x + threadIdx.x) * 8;
  const f32x4* p = (const f32x4*)(X + base);
  f32x4 v0 = __builtin_nontemporal_load(p);
  f32x4 v1 = __builtin_nontemporal_load(p + 1);
  uint4 pk;
  pk.x = (unsigned)f2bf(v0.x) | ((unsigned)f2bf(v0.y) << 16);
  pk.y = (unsigned)f2bf(v0.z) | ((unsigned)f2bf(v0.w) << 16);
  pk.z = (unsigned)f2bf(v1.x) | ((unsigned)f2bf(v1.y) << 16);
  pk.w = (unsigned)f2bf(v1.z) | ((unsigned)f2bf(v1.w) << 16);
  *(uint4*)(Xb + base) = pk;
}

// ---------------------------------------------------------------------------
// GEMM (round-11): r10's proven 2-barrier 16-wave schedule, with the X f32->
// bf16 conversion FUSED into A-staging (removes the 201 MB X-pass from prep).
// A-path: reg-stage -- f32 loads issued in h0 (after ds_reads), WAIT0 + cvt +
// ds_write into A[b^1] at h1 tail, lgkmcnt(0) before next barrier. Strictly
// barrier-sound: A[b^1] readers run only after bar(t+1,h0); writers' ds_writes
// drained per-wave before that barrier.
// B-path: unchanged r8/r10 2-ahead gload_lds pattern (5 clean runs).
// vmcnt ledger: at bar(t,h0) outstanding = B(t+1)x2; h0 issues 4 A-f32 float4
// loads -> 6; h1-tail WAIT0 drains all (B(t+1) lands early, harmless); then
// cvt+write+STAGE_B(t+2)x2 -> outstanding 2 entering t+1. Steady state.

#define ABASE(b) ((b) * 32768)
#define BBASE(b) ((b) * 32768 + 16384)

#define STAGE_B(b, h, kt) \
  gload_lds16(bG + (size_t)((h) * 128) * IN_F + (kt), lds + BBASE(b) + ((h) * 128) * 64 + tid * 8)

// issue 4 float4 loads of X (f32) for tile kt, both halves
#define LOAD_A(kt) do { \
  av00 = *(const f32x4*)(xG + (size_t)(kt)); \
  av01 = *(const f32x4*)(xG + (size_t)(kt) + 4); \
  av10 = *(const f32x4*)(xG + (size_t)128 * IN_F + (kt)); \
  av11 = *(const f32x4*)(xG + (size_t)128 * IN_F + (kt) + 4); \
} while (0)

// convert + write into A[b] (both halves), linear dest tid*8 (u16 units)
#define CVT_WRITE_A(b) do { \
  uint4 p0, p1; \
  p0.x = (unsigned)f2bf(av00.x) | ((unsigned)f2bf(av00.y) << 16); \
  p0.y = (unsigned)f2bf(av00.z) | ((unsigned)f2bf(av00.w) << 16); \
  p0.z = (unsigned)f2bf(av01.x) | ((unsigned)f2bf(av01.y) << 16); \
  p0.w = (unsigned)f2bf(av01.z) | ((unsigned)f2bf(av01.w) << 16); \
  p1.x = (unsigned)f2bf(av10.x) | ((unsigned)f2bf(av10.y) << 16); \
  p1.y = (unsigned)f2bf(av10.z) | ((unsigned)f2bf(av10.w) << 16); \
  p1.z = (unsigned)f2bf(av11.x) | ((unsigned)f2bf(av11.y) << 16); \
  p1.w = (unsigned)f2bf(av11.z) | ((unsigned)f2bf(av11.w) << 16); \
  *(uint4*)(lds + ABASE(b) + tid * 8) = p0; \
  *(uint4*)(lds + ABASE(b) + 8192 + tid * 8) = p1; \
} while (0)

#define WAIT0 asm volatile("s_waitcnt vmcnt(0)" ::: "memory")
#define LGKM0 asm volatile("s_waitcnt lgkmcnt(0)" ::: "memory")

#define MFMA16 __builtin_amdgcn_mfma_f32_16x16x32_bf16

// One K-tile half: 8 ds_reads + optional A-f32 issue + 16 MFMA + tail.
#define KHALF(b, CKX, MID_STMT, TAIL_STMT) do { \
  __builtin_amdgcn_s_barrier(); \
  __builtin_amdgcn_sched_barrier(0); \
  _Pragma("unroll") \
  for (int n = 0; n < 4; ++n) \
    Bf[n] = *(const bf16x8*)(lds + BBASE(b) + (rB + n * 16) * 64 + (CKX)); \
  _Pragma("unroll") \
  for (int m = 0; m < 4; ++m) \
    Af[m] = *(const bf16x8*)(lds + ABASE(b) + (rA + m * 16) * 64 + (CKX)); \
  MID_STMT; \
  __builtin_amdgcn_s_setprio(1); \
  _Pragma("unroll") \
  for (int m = 0; m < 4; ++m) \
    _Pragma("unroll") \
    for (int n = 0; n < 4; ++n) \
      acc[m][n] = MFMA16(Af[m], Bf[n], acc[m][n], 0, 0, 0); \
  __builtin_amdgcn_s_setprio(0); \
  TAIL_STMT; \
} while (0)

__global__ __launch_bounds__(1024, 4) void gemm8(const float* __restrict__ X,
                                                 const u16* __restrict__ Wb,
                                                 const float* __restrict__ bias,
                                                 float* __restrict__ out) {
  extern __shared__ u16 lds[];

  const int tid  = threadIdx.x;
  const int lane = tid & 63;
  const int wid  = tid >> 6;                   // 0..15
  const int wr = wid >> 2, wc = wid & 3;       // 4x4 waves, 64x64 C each
  const int lr = lane & 15, kg = lane >> 4;

  // XCD-aware swizzle: nwg = 512, divisible by 8
  const int bid = blockIdx.x;
  const int swz = (bid & 7) * 64 + (bid >> 3);
  const int mt = swz >> 4, nt = swz & 15;       // 32 M-tiles x 16 N-tiles
  const int m0 = mt * 256, n0 = nt * 256;

  // staging geometry (1024 threads): srow 0..127, pre-swizzled chunk^(row&7)
  const int srow = tid >> 3;
  const int swc  = (tid & 7) ^ (srow & 7);
  const float* xG = X + (size_t)(m0 + srow) * IN_F + swc * 8;   // f32 source
  const u16*   bG = Wb + (size_t)(n0 + srow) * IN_F + swc * 8;  // bf16 source

  // fragment read offsets (proven 0-conflict 16x16 pattern)
  const int rA = wr * 64 + lr;
  const int rB = wc * 64 + lr;
  const int ck0 = ((kg) ^ (lane & 7)) * 8;       // k-slice 0
  const int ck1 = ((4 + kg) ^ (lane & 7)) * 8;   // k-slice 1

  f32x4 acc[4][4] = {};
  bf16x8 Af[4], Bf[4];
  f32x4 av00, av01, av10, av11;

  // prologue: B0 gloads + A0 f32 loads; WAIT0; cvt/write A0; B1 gloads; lgkm0
  STAGE_B(0, 0, 0); STAGE_B(0, 1, 0);
  LOAD_A(0);
  WAIT0;
  CVT_WRITE_A(0);
  STAGE_B(1, 0, 64); STAGE_B(1, 1, 64);
  LGKM0;

  for (int i = 0; i < 31; ++i) {
    const int kt1 = i * 128 + 64, kt2 = i * 128 + 128, kt3 = i * 128 + 192;
    // tile 2i (buffer 0): A(2i+1) f32 loaded in h0, written to buf1 in h1 tail
    KHALF(0, ck0, LOAD_A(kt1), );
    KHALF(0, ck1, ,
          WAIT0; CVT_WRITE_A(1); STAGE_B(0, 0, kt2); STAGE_B(0, 1, kt2); LGKM0);
    // tile 2i+1 (buffer 1): A(2i+2) f32 loaded in h0, written to buf0
    KHALF(1, ck0, LOAD_A(kt2), );
    KHALF(1, ck1, ,
          WAIT0; CVT_WRITE_A(0); STAGE_B(1, 0, kt3); STAGE_B(1, 1, kt3); LGKM0);
  }
  // tile 62 (buf 0): load+write A(63); B(63) already staged (tile 61)
  KHALF(0, ck0, LOAD_A(4032), );
  KHALF(0, ck1, , WAIT0; CVT_WRITE_A(1); LGKM0);
  // tile 63 (buf 1): pure compute
  KHALF(1, ck0, , );
  KHALF(1, ck1, , );

  // C write + bias (nontemporal). C/D layout: col = lane&15, row = kg*4 + reg
  float bv[4];
#pragma unroll
  for (int n = 0; n < 4; ++n) bv[n] = bias[n0 + wc * 64 + n * 16 + lr];
  const int rbase = m0 + wr * 64 + kg * 4;
#pragma unroll
  for (int m = 0; m < 4; ++m)
#pragma unroll
    for (int n = 0; n < 4; ++n) {
      int col = n0 + wc * 64 + n * 16 + lr;
#pragma unroll
      for (int r = 0; r < 4; ++r)
        __builtin_nontemporal_store(acc[m][n][r] + bv[n],
                                    &out[(size_t)(rbase + m * 16 + r) * OUT_F + col]);
    }
}

// ---------------------------------------------------------------------------
// Fallback GEMM (proven round-1 kernel): 128x128 tile, m97 structure, 859 TF.
__global__ __launch_bounds__(256) void gemm_bias(const u16* __restrict__ Xb,
                                                 const u16* __restrict__ Wb,
                                                 const float* __restrict__ bias,
                                                 float* __restrict__ out) {
  __shared__ __align__(16) u16 ldsA[128 * 64];
  __shared__ __align__(16) u16 ldsB[128 * 64];

  const int tid  = threadIdx.x;
  const int wid  = tid >> 6;
  const int lane = tid & 63;
  const int nt = blockIdx.x & 31;
  const int mt = blockIdx.x >> 5;
  const int m0 = mt * 128, n0 = nt * 128;
  const int wr = wid >> 1, wc = wid & 1;
  const int lr = lane & 15;
  const int kg = lane >> 4;

  const int srow   = wid * 8 + (lane >> 3);
  const int schunk = (lane & 7) ^ (srow & 7);
  const u16* aSrc = Xb + (size_t)(m0 + srow) * IN_F + schunk * 8;
  const u16* bSrc = Wb + (size_t)(n0 + srow) * IN_F + schunk * 8;

  f32x4 acc[4][4] = {};

  for (int kt = 0; kt < IN_F; kt += 64) {
    __syncthreads();
#pragma unroll
    for (int j = 0; j < 4; ++j) {
      gload_lds16(aSrc + (size_t)(j * 32) * IN_F + kt, &ldsA[j * 2048 + wid * 512]);
      gload_lds16(bSrc + (size_t)(j * 32) * IN_F + kt, &ldsB[j * 2048 + wid * 512]);
    }
    __syncthreads();

#pragma unroll
    for (int s = 0; s < 2; ++s) {
      bf16x8 af[4], bfr[4];
#pragma unroll
      for (int m = 0; m < 4; ++m) {
        int r = wr * 64 + m * 16 + lr;
        int c = (s * 4 + kg) ^ (r & 7);
        af[m] = *(const bf16x8*)&ldsA[r * 64 + c * 8];
      }
#pragma unroll
      for (int n = 0; n < 4; ++n) {
        int r = wc * 64 + n * 16 + lr;
        int c = (s * 4 + kg) ^ (r & 7);
        bfr[n] = *(const bf16x8*)&ldsB[r * 64 + c * 8];
      }
#pragma unroll
      for (int m = 0; m < 4; ++m)
#pragma unroll
        for (int n = 0; n < 4; ++n)
          acc[m][n] = __builtin_amdgcn_mfma_f32_16x16x32_bf16(af[m], bfr[n], acc[m][n], 0, 0, 0);
    }
  }

  float bv[4];
#pragma unroll
  for (int n = 0; n < 4; ++n) bv[n] = bias[n0 + wc * 64 + n * 16 + lr];
  const int rbase = m0 + wr * 64 + kg * 4;
#pragma unroll
  for (int m = 0; m < 4; ++m)
#pragma unroll
    for (int n = 0; n < 4; ++n) {
      int col = n0 + wc * 64 + n * 16 + lr;
#pragma unroll
      for (int r = 0; r < 4; ++r)
        out[(size_t)(rbase + m * 16 + r) * OUT_F + col] = acc[m][n][r] + bv[n];
    }
}

// ---------------------------------------------------------------------------
// fp32 fallback (tiny workspace): exact, slow but correct.
__global__ void lora_t(const float* __restrict__ x, const float* __restrict__ B,
                       float* __restrict__ t) {
  int m = blockIdx.x;
  int tid = threadIdx.x, lane = tid & 63;
  float p[8] = {0, 0, 0, 0, 0, 0, 0, 0};
  for (int k = tid; k < IN_F; k += 256) {
    float xv = x[(size_t)m * IN_F + k];
#pragma unroll
    for (int r = 0; r < 8; ++r) p[r] += xv * B[r * IN_F + k];
  }
#pragma unroll
  for (int r = 0; r < 8; ++r) {
    float v = p[r];
    for (int off = 32; off; off >>= 1) v += __shfl_down(v, off);
    if (lane == 0) atomicAdd(&t[m * 8 + r], v);
  }
}

__global__ void fb_gemm(const float* __restrict__ x, const float* __restrict__ W,
                        const float* __restrict__ A, const float* __restrict__ bias,
                        const float* __restrict__ t, float* __restrict__ out) {
  __shared__ float sx[64][17];
  __shared__ float sw[64][17];
  int tx = threadIdx.x, ty = threadIdx.y;
  int tid = ty * 16 + tx;
  int m0 = blockIdx.y * 64, n0 = blockIdx.x * 64;
  float acc[4][4] = {};
  for (int kt = 0; kt < IN_F; kt += 16) {
    __syncthreads();
#pragma unroll
    for (int q = 0; q < 4; ++q) {
      int idx = q * 256 + tid;
      int r = idx >> 4, c = idx & 15;
      sx[r][c] = x[(size_t)(m0 + r) * IN_F + kt + c];
      sw[r][c] = W[(size_t)(n0 + r) * IN_F + kt + c];
    }
    __syncthreads();
#pragma unroll
    for (int k = 0; k < 16; ++k) {
      float xv[4], wv[4];
#pragma unroll
      for (int i = 0; i < 4; ++i) xv[i] = sx[ty * 4 + i][k];
#pragma unroll
      for (int j = 0; j < 4; ++j) wv[j] = sw[tx * 4 + j][k];
#pragma unroll
      for (int i = 0; i < 4; ++i)
#pragma unroll
        for (int j = 0; j < 4; ++j) acc[i][j] += xv[i] * wv[j];
    }
  }
#pragma unroll
  for (int i = 0; i < 4; ++i) {
    int m = m0 + ty * 4 + i;
    float tv[8];
#pragma unroll
    for (int r = 0; r < 8; ++r) tv[r] = t[m * 8 + r];
#pragma unroll
    for (int j = 0; j < 4; ++j) {
      int o = n0 + tx * 4 + j;
      float lora = 0.f;
#pragma unroll
      for (int r = 0; r < 8; ++r) lora += tv[r] * A[o * 8 + r];
      out[(size_t)m * OUT_F + o] = acc[i][j] + bias[o] + LORA_SCALE * lora;
    }
  }
}

// ---------------------------------------------------------------------------
extern "C" void kernel_launch(void* const* d_in, const int* in_sizes, int n_in,
                              void* d_out, int out_size, void* d_ws, size_t ws_size,
                              hipStream_t stream) {
  const float* x    = (const float*)d_in[0];
  const float* W    = (const float*)d_in[1];
  const float* A    = (const float*)d_in[2];
  const float* B    = (const float*)d_in[3];
  const float* bias = (const float*)d_in[4];
  float* out = (float*)d_out;

  const size_t xb_elems = (size_t)M_TOT * IN_F;
  const size_t wb_elems = (size_t)OUT_F * IN_F;

  if (ws_size >= (xb_elems + wb_elems) * sizeof(u16)) {
    u16* Xb = (u16*)d_ws;                 // used only by fallback
    u16* Wb = Xb + xb_elems;
    prep_w<<<16384, 256, 0, stream>>>(W, A, B, Wb);

    hipError_t e = hipFuncSetAttribute((const void*)gemm8,
                                       hipFuncAttributeMaxDynamicSharedMemorySize,
                                       131072);
    bool used8 = false;
    if (e == hipSuccess) {
      gemm8<<<512, 1024, 131072, stream>>>(x, Wb, bias, out);
      used8 = (hipGetLastError() == hipSuccess);
    }
    if (!used8) {
      convert_x<<<(M_TOT * IN_F / 8) / 256, 256, 0, stream>>>(x, Xb);
      gemm_bias<<<(M_TOT / 128) * (OUT_F / 128), 256, 0, stream>>>(Xb, Wb, bias, out);
    }
  } else {
    float* t = (float*)d_ws;
    (void)hipMemsetAsync(t, 0, (size_t)M_TOT * 8 * sizeof(float), stream);
    lora_t<<<M_TOT, 256, 0, stream>>>(x, B, t);
    fb_gemm<<<dim3(OUT_F / 64, M_TOT / 64), dim3(16, 16), 0, stream>>>(x, W, A, bias, t, out);
  }
}

// Round 12
// 697.783 us; speedup vs baseline: 1.0010x; 1.0010x over previous
//
#include <hip/hip_runtime.h>
#include <stdint.h>

#define IN_F 4096
#define OUT_F 4096
#define M_TOT 8192
#define LORA_SCALE 4.0f   // ALPHA / RANK = 32 / 8

typedef unsigned short u16;
typedef __attribute__((ext_vector_type(8))) short bf16x8;   // 8 bf16 = 4 VGPRs
typedef __attribute__((ext_vector_type(4))) float f32x4;

__device__ __forceinline__ u16 f2bf(float f) {
  union { float f; unsigned u; } v; v.f = f;
  unsigned r = v.u + 0x7FFFu + ((v.u >> 16) & 1u);  // round-to-nearest-even
  return (u16)(r >> 16);
}

__device__ __forceinline__ void gload_lds16(const void* g, void* l) {
  __builtin_amdgcn_global_load_lds(
      (const __attribute__((address_space(1))) void*)g,
      (__attribute__((address_space(3))) void*)l, 16, 0, 0);
}

// ---------------------------------------------------------------------------
// Prep (Wb only): Wb[o][i] = bf16( W[o][i] + 4 * sum_r a[o][r]*b[r][i] )
__global__ void prep_w(const float* __restrict__ W, const float* __restrict__ A,
                       const float* __restrict__ B, u16* __restrict__ Wb) {
  int idx = blockIdx.x * blockDim.x + threadIdx.x;
  int o  = idx >> 10;
  int i0 = (idx & 1023) << 2;
  const f32x4 w = __builtin_nontemporal_load((const f32x4*)(W + (size_t)o * IN_F + i0));
  float a0 = w.x, a1 = w.y, a2 = w.z, a3 = w.w;
#pragma unroll
  for (int r = 0; r < 8; ++r) {
    float ar = A[o * 8 + r] * LORA_SCALE;
    const float4 bv = *(const float4*)(B + (size_t)r * IN_F + i0);
    a0 += ar * bv.x; a1 += ar * bv.y; a2 += ar * bv.z; a3 += ar * bv.w;
  }
  uint2 pk;
  pk.x = (unsigned)f2bf(a0) | ((unsigned)f2bf(a1) << 16);
  pk.y = (unsigned)f2bf(a2) | ((unsigned)f2bf(a3) << 16);
  *(uint2*)(Wb + (size_t)o * IN_F + i0) = pk;
}

// Fallback-path X conversion (only used if gemm8 can't launch)
__global__ void convert_x(const float* __restrict__ X, u16* __restrict__ Xb) {
  size_t base = ((size_t)blockIdx.x * blockDim.x + threadIdx.x) * 8;
  const f32x4* p = (const f32x4*)(X + base);
  f32x4 v0 = __builtin_nontemporal_load(p);
  f32x4 v1 = __builtin_nontemporal_load(p + 1);
  uint4 pk;
  pk.x = (unsigned)f2bf(v0.x) | ((unsigned)f2bf(v0.y) << 16);
  pk.y = (unsigned)f2bf(v0.z) | ((unsigned)f2bf(v0.w) << 16);
  pk.z = (unsigned)f2bf(v1.x) | ((unsigned)f2bf(v1.y) << 16);
  pk.w = (unsigned)f2bf(v1.z) | ((unsigned)f2bf(v1.w) << 16);
  *(uint4*)(Xb + base) = pk;
}

// ---------------------------------------------------------------------------
// GEMM (round-12): r11's fused-conversion schedule, register-bound FIXED.
// r11 bug: __launch_bounds__(1024,4) capped waves at 128 unified regs; the
// 16 live av-VGPRs pushed past it -> scratch spills -> 870 MB extra HBM
// writes -> 855 us. Occupancy is LDS-capped at 1 block/CU (= 4 waves/SIMD)
// anyway, so the reg cap buys nothing: relax to (1024,2) = 256 regs/wave.
// Schedule, ledger, and race audit identical to r11 (barrier-sound A-write:
// WAIT0+cvt+ds_write at h1 tail, LGKM0 before next barrier; B via proven
// 2-ahead gload_lds).

#define ABASE(b) ((b) * 32768)
#define BBASE(b) ((b) * 32768 + 16384)

#define STAGE_B(b, h, kt) \
  gload_lds16(bG + (size_t)((h) * 128) * IN_F + (kt), lds + BBASE(b) + ((h) * 128) * 64 + tid * 8)

// issue 4 float4 loads of X (f32) for tile kt, both halves
#define LOAD_A(kt) do { \
  av00 = *(const f32x4*)(xG + (size_t)(kt)); \
  av01 = *(const f32x4*)(xG + (size_t)(kt) + 4); \
  av10 = *(const f32x4*)(xG + (size_t)128 * IN_F + (kt)); \
  av11 = *(const f32x4*)(xG + (size_t)128 * IN_F + (kt) + 4); \
} while (0)

// convert + write into A[b] (both halves), linear dest tid*8 (u16 units)
#define CVT_WRITE_A(b) do { \
  uint4 p0, p1; \
  p0.x = (unsigned)f2bf(av00.x) | ((unsigned)f2bf(av00.y) << 16); \
  p0.y = (unsigned)f2bf(av00.z) | ((unsigned)f2bf(av00.w) << 16); \
  p0.z = (unsigned)f2bf(av01.x) | ((unsigned)f2bf(av01.y) << 16); \
  p0.w = (unsigned)f2bf(av01.z) | ((unsigned)f2bf(av01.w) << 16); \
  p1.x = (unsigned)f2bf(av10.x) | ((unsigned)f2bf(av10.y) << 16); \
  p1.y = (unsigned)f2bf(av10.z) | ((unsigned)f2bf(av10.w) << 16); \
  p1.z = (unsigned)f2bf(av11.x) | ((unsigned)f2bf(av11.y) << 16); \
  p1.w = (unsigned)f2bf(av11.z) | ((unsigned)f2bf(av11.w) << 16); \
  *(uint4*)(lds + ABASE(b) + tid * 8) = p0; \
  *(uint4*)(lds + ABASE(b) + 8192 + tid * 8) = p1; \
} while (0)

#define WAIT0 asm volatile("s_waitcnt vmcnt(0)" ::: "memory")
#define LGKM0 asm volatile("s_waitcnt lgkmcnt(0)" ::: "memory")

#define MFMA16 __builtin_amdgcn_mfma_f32_16x16x32_bf16

// One K-tile half: 8 ds_reads + optional A-f32 issue + 16 MFMA + tail.
#define KHALF(b, CKX, MID_STMT, TAIL_STMT) do { \
  __builtin_amdgcn_s_barrier(); \
  __builtin_amdgcn_sched_barrier(0); \
  _Pragma("unroll") \
  for (int n = 0; n < 4; ++n) \
    Bf[n] = *(const bf16x8*)(lds + BBASE(b) + (rB + n * 16) * 64 + (CKX)); \
  _Pragma("unroll") \
  for (int m = 0; m < 4; ++m) \
    Af[m] = *(const bf16x8*)(lds + ABASE(b) + (rA + m * 16) * 64 + (CKX)); \
  MID_STMT; \
  __builtin_amdgcn_s_setprio(1); \
  _Pragma("unroll") \
  for (int m = 0; m < 4; ++m) \
    _Pragma("unroll") \
    for (int n = 0; n < 4; ++n) \
      acc[m][n] = MFMA16(Af[m], Bf[n], acc[m][n], 0, 0, 0); \
  __builtin_amdgcn_s_setprio(0); \
  TAIL_STMT; \
} while (0)

__global__ __launch_bounds__(1024, 2) void gemm8(const float* __restrict__ X,
                                                 const u16* __restrict__ Wb,
                                                 const float* __restrict__ bias,
                                                 float* __restrict__ out) {
  extern __shared__ u16 lds[];

  const int tid  = threadIdx.x;
  const int lane = tid & 63;
  const int wid  = tid >> 6;                   // 0..15
  const int wr = wid >> 2, wc = wid & 3;       // 4x4 waves, 64x64 C each
  const int lr = lane & 15, kg = lane >> 4;

  // XCD-aware swizzle: nwg = 512, divisible by 8
  const int bid = blockIdx.x;
  const int swz = (bid & 7) * 64 + (bid >> 3);
  const int mt = swz >> 4, nt = swz & 15;       // 32 M-tiles x 16 N-tiles
  const int m0 = mt * 256, n0 = nt * 256;

  // staging geometry (1024 threads): srow 0..127, pre-swizzled chunk^(row&7)
  const int srow = tid >> 3;
  const int swc  = (tid & 7) ^ (srow & 7);
  const float* xG = X + (size_t)(m0 + srow) * IN_F + swc * 8;   // f32 source
  const u16*   bG = Wb + (size_t)(n0 + srow) * IN_F + swc * 8;  // bf16 source

  // fragment read offsets (proven 0-conflict 16x16 pattern)
  const int rA = wr * 64 + lr;
  const int rB = wc * 64 + lr;
  const int ck0 = ((kg) ^ (lane & 7)) * 8;       // k-slice 0
  const int ck1 = ((4 + kg) ^ (lane & 7)) * 8;   // k-slice 1

  f32x4 acc[4][4] = {};
  bf16x8 Af[4], Bf[4];
  f32x4 av00, av01, av10, av11;

  // prologue: B0 gloads + A0 f32 loads; WAIT0; cvt/write A0; B1 gloads; lgkm0
  STAGE_B(0, 0, 0); STAGE_B(0, 1, 0);
  LOAD_A(0);
  WAIT0;
  CVT_WRITE_A(0);
  STAGE_B(1, 0, 64); STAGE_B(1, 1, 64);
  LGKM0;

  for (int i = 0; i < 31; ++i) {
    const int kt1 = i * 128 + 64, kt2 = i * 128 + 128, kt3 = i * 128 + 192;
    // tile 2i (buffer 0): A(2i+1) f32 loaded in h0, written to buf1 in h1 tail
    KHALF(0, ck0, LOAD_A(kt1), );
    KHALF(0, ck1, ,
          WAIT0; CVT_WRITE_A(1); STAGE_B(0, 0, kt2); STAGE_B(0, 1, kt2); LGKM0);
    // tile 2i+1 (buffer 1): A(2i+2) f32 loaded in h0, written to buf0
    KHALF(1, ck0, LOAD_A(kt2), );
    KHALF(1, ck1, ,
          WAIT0; CVT_WRITE_A(0); STAGE_B(1, 0, kt3); STAGE_B(1, 1, kt3); LGKM0);
  }
  // tile 62 (buf 0): load+write A(63); B(63) already staged (tile 61)
  KHALF(0, ck0, LOAD_A(4032), );
  KHALF(0, ck1, , WAIT0; CVT_WRITE_A(1); LGKM0);
  // tile 63 (buf 1): pure compute
  KHALF(1, ck0, , );
  KHALF(1, ck1, , );

  // C write + bias (nontemporal). C/D layout: col = lane&15, row = kg*4 + reg
  float bv[4];
#pragma unroll
  for (int n = 0; n < 4; ++n) bv[n] = bias[n0 + wc * 64 + n * 16 + lr];
  const int rbase = m0 + wr * 64 + kg * 4;
#pragma unroll
  for (int m = 0; m < 4; ++m)
#pragma unroll
    for (int n = 0; n < 4; ++n) {
      int col = n0 + wc * 64 + n * 16 + lr;
#pragma unroll
      for (int r = 0; r < 4; ++r)
        __builtin_nontemporal_store(acc[m][n][r] + bv[n],
                                    &out[(size_t)(rbase + m * 16 + r) * OUT_F + col]);
    }
}

// ---------------------------------------------------------------------------
// Fallback GEMM (proven round-1 kernel): 128x128 tile, m97 structure, 859 TF.
__global__ __launch_bounds__(256) void gemm_bias(const u16* __restrict__ Xb,
                                                 const u16* __restrict__ Wb,
                                                 const float* __restrict__ bias,
                                                 float* __restrict__ out) {
  __shared__ __align__(16) u16 ldsA[128 * 64];
  __shared__ __align__(16) u16 ldsB[128 * 64];

  const int tid  = threadIdx.x;
  const int wid  = tid >> 6;
  const int lane = tid & 63;
  const int nt = blockIdx.x & 31;
  const int mt = blockIdx.x >> 5;
  const int m0 = mt * 128, n0 = nt * 128;
  const int wr = wid >> 1, wc = wid & 1;
  const int lr = lane & 15;
  const int kg = lane >> 4;

  const int srow   = wid * 8 + (lane >> 3);
  const int schunk = (lane & 7) ^ (srow & 7);
  const u16* aSrc = Xb + (size_t)(m0 + srow) * IN_F + schunk * 8;
  const u16* bSrc = Wb + (size_t)(n0 + srow) * IN_F + schunk * 8;

  f32x4 acc[4][4] = {};

  for (int kt = 0; kt < IN_F; kt += 64) {
    __syncthreads();
#pragma unroll
    for (int j = 0; j < 4; ++j) {
      gload_lds16(aSrc + (size_t)(j * 32) * IN_F + kt, &ldsA[j * 2048 + wid * 512]);
      gload_lds16(bSrc + (size_t)(j * 32) * IN_F + kt, &ldsB[j * 2048 + wid * 512]);
    }
    __syncthreads();

#pragma unroll
    for (int s = 0; s < 2; ++s) {
      bf16x8 af[4], bfr[4];
#pragma unroll
      for (int m = 0; m < 4; ++m) {
        int r = wr * 64 + m * 16 + lr;
        int c = (s * 4 + kg) ^ (r & 7);
        af[m] = *(const bf16x8*)&ldsA[r * 64 + c * 8];
      }
#pragma unroll
      for (int n = 0; n < 4; ++n) {
        int r = wc * 64 + n * 16 + lr;
        int c = (s * 4 + kg) ^ (r & 7);
        bfr[n] = *(const bf16x8*)&ldsB[r * 64 + c * 8];
      }
#pragma unroll
      for (int m = 0; m < 4; ++m)
#pragma unroll
        for (int n = 0; n < 4; ++n)
          acc[m][n] = __builtin_amdgcn_mfma_f32_16x16x32_bf16(af[m], bfr[n], acc[m][n], 0, 0, 0);
    }
  }

  float bv[4];
#pragma unroll
  for (int n = 0; n < 4; ++n) bv[n] = bias[n0 + wc * 64 + n * 16 + lr];
  const int rbase = m0 + wr * 64 + kg * 4;
#pragma unroll
  for (int m = 0; m < 4; ++m)
#pragma unroll
    for (int n = 0; n < 4; ++n) {
      int col = n0 + wc * 64 + n * 16 + lr;
#pragma unroll
      for (int r = 0; r < 4; ++r)
        out[(size_t)(rbase + m * 16 + r) * OUT_F + col] = acc[m][n][r] + bv[n];
    }
}

// ---------------------------------------------------------------------------
// fp32 fallback (tiny workspace): exact, slow but correct.
__global__ void lora_t(const float* __restrict__ x, const float* __restrict__ B,
                       float* __restrict__ t) {
  int m = blockIdx.x;
  int tid = threadIdx.x, lane = tid & 63;
  float p[8] = {0, 0, 0, 0, 0, 0, 0, 0};
  for (int k = tid; k < IN_F; k += 256) {
    float xv = x[(size_t)m * IN_F + k];
#pragma unroll
    for (int r = 0; r < 8; ++r) p[r] += xv * B[r * IN_F + k];
  }
#pragma unroll
  for (int r = 0; r < 8; ++r) {
    float v = p[r];
    for (int off = 32; off; off >>= 1) v += __shfl_down(v, off);
    if (lane == 0) atomicAdd(&t[m * 8 + r], v);
  }
}

__global__ void fb_gemm(const float* __restrict__ x, const float* __restrict__ W,
                        const float* __restrict__ A, const float* __restrict__ bias,
                        const float* __restrict__ t, float* __restrict__ out) {
  __shared__ float sx[64][17];
  __shared__ float sw[64][17];
  int tx = threadIdx.x, ty = threadIdx.y;
  int tid = ty * 16 + tx;
  int m0 = blockIdx.y * 64, n0 = blockIdx.x * 64;
  float acc[4][4] = {};
  for (int kt = 0; kt < IN_F; kt += 16) {
    __syncthreads();
#pragma unroll
    for (int q = 0; q < 4; ++q) {
      int idx = q * 256 + tid;
      int r = idx >> 4, c = idx & 15;
      sx[r][c] = x[(size_t)(m0 + r) * IN_F + kt + c];
      sw[r][c] = W[(size_t)(n0 + r) * IN_F + kt + c];
    }
    __syncthreads();
#pragma unroll
    for (int k = 0; k < 16; ++k) {
      float xv[4], wv[4];
#pragma unroll
      for (int i = 0; i < 4; ++i) xv[i] = sx[ty * 4 + i][k];
#pragma unroll
      for (int j = 0; j < 4; ++j) wv[j] = sw[tx * 4 + j][k];
#pragma unroll
      for (int i = 0; i < 4; ++i)
#pragma unroll
        for (int j = 0; j < 4; ++j) acc[i][j] += xv[i] * wv[j];
    }
  }
#pragma unroll
  for (int i = 0; i < 4; ++i) {
    int m = m0 + ty * 4 + i;
    float tv[8];
#pragma unroll
    for (int r = 0; r < 8; ++r) tv[r] = t[m * 8 + r];
#pragma unroll
    for (int j = 0; j < 4; ++j) {
      int o = n0 + tx * 4 + j;
      float lora = 0.f;
#pragma unroll
      for (int r = 0; r < 8; ++r) lora += tv[r] * A[o * 8 + r];
      out[(size_t)m * OUT_F + o] = acc[i][j] + bias[o] + LORA_SCALE * lora;
    }
  }
}

// ---------------------------------------------------------------------------
extern "C" void kernel_launch(void* const* d_in, const int* in_sizes, int n_in,
                              void* d_out, int out_size, void* d_ws, size_t ws_size,
                              hipStream_t stream) {
  const float* x    = (const float*)d_in[0];
  const float* W    = (const float*)d_in[1];
  const float* A    = (const float*)d_in[2];
  const float* B    = (const float*)d_in[3];
  const float* bias = (const float*)d_in[4];
  float* out = (float*)d_out;

  const size_t xb_elems = (size_t)M_TOT * IN_F;
  const size_t wb_elems = (size_t)OUT_F * IN_F;

  if (ws_size >= (xb_elems + wb_elems) * sizeof(u16)) {
    u16* Xb = (u16*)d_ws;                 // used only by fallback
    u16* Wb = Xb + xb_elems;
    prep_w<<<16384, 256, 0, stream>>>(W, A, B, Wb);

    hipError_t e = hipFuncSetAttribute((const void*)gemm8,
                                       hipFuncAttributeMaxDynamicSharedMemorySize,
                                       131072);
    bool used8 = false;
    if (e == hipSuccess) {
      gemm8<<<512, 1024, 131072, stream>>>(x, Wb, bias, out);
      used8 = (hipGetLastError() == hipSuccess);
    }
    if (!used8) {
      convert_x<<<(M_TOT * IN_F / 8) / 256, 256, 0, stream>>>(x, Xb);
      gemm_bias<<<(M_TOT / 128) * (OUT_F / 128), 256, 0, stream>>>(Xb, Wb, bias, out);
    }
  } else {
    float* t = (float*)d_ws;
    (void)hipMemsetAsync(t, 0, (size_t)M_TOT * 8 * sizeof(float), stream);
    lora_t<<<M_TOT, 256, 0, stream>>>(x, B, t);
    fb_gemm<<<dim3(OUT_F / 64, M_TOT / 64), dim3(16, 16), 0, stream>>>(x, W, A, bias, t, out);
  }
}

// Round 13
// 296.380 us; speedup vs baseline: 2.3568x; 2.3544x over previous
//
#include <hip/hip_runtime.h>
#include <stdint.h>

#define IN_F 4096
#define OUT_F 4096
#define M_TOT 8192
#define LORA_SCALE 4.0f   // ALPHA / RANK = 32 / 8

typedef unsigned short u16;
typedef __attribute__((ext_vector_type(8))) short bf16x8;   // 8 bf16 = 4 VGPRs
typedef __attribute__((ext_vector_type(4))) float f32x4;

__device__ __forceinline__ u16 f2bf(float f) {
  union { float f; unsigned u; } v; v.f = f;
  unsigned r = v.u + 0x7FFFu + ((v.u >> 16) & 1u);  // round-to-nearest-even
  return (u16)(r >> 16);
}

__device__ __forceinline__ void gload_lds16(const void* g, void* l) {
  __builtin_amdgcn_global_load_lds(
      (const __attribute__((address_space(1))) void*)g,
      (__attribute__((address_space(3))) void*)l, 16, 0, 0);
}

// ---------------------------------------------------------------------------
// Fused prep (r10 proven): blocks [0,16384): Xb = bf16(x)
//                          blocks [16384,32768): Wb = bf16(W + 4*a@b)
__global__ void prep(const float* __restrict__ X, const float* __restrict__ W,
                     const float* __restrict__ A, const float* __restrict__ B,
                     u16* __restrict__ Xb, u16* __restrict__ Wb) {
  int bid = blockIdx.x;
  if (bid < 16384) {
    size_t base = ((size_t)bid * blockDim.x + threadIdx.x) * 8;
    const f32x4* p = (const f32x4*)(X + base);
    f32x4 v0 = __builtin_nontemporal_load(p);
    f32x4 v1 = __builtin_nontemporal_load(p + 1);
    uint4 pk;
    pk.x = (unsigned)f2bf(v0.x) | ((unsigned)f2bf(v0.y) << 16);
    pk.y = (unsigned)f2bf(v0.z) | ((unsigned)f2bf(v0.w) << 16);
    pk.z = (unsigned)f2bf(v1.x) | ((unsigned)f2bf(v1.y) << 16);
    pk.w = (unsigned)f2bf(v1.z) | ((unsigned)f2bf(v1.w) << 16);
    *(uint4*)(Xb + base) = pk;
  } else {
    int idx = (bid - 16384) * blockDim.x + threadIdx.x;
    int o  = idx >> 10;
    int i0 = (idx & 1023) << 2;
    const f32x4 w = __builtin_nontemporal_load((const f32x4*)(W + (size_t)o * IN_F + i0));
    float a0 = w.x, a1 = w.y, a2 = w.z, a3 = w.w;
#pragma unroll
    for (int r = 0; r < 8; ++r) {
      float ar = A[o * 8 + r] * LORA_SCALE;
      const float4 bv = *(const float4*)(B + (size_t)r * IN_F + i0);
      a0 += ar * bv.x; a1 += ar * bv.y; a2 += ar * bv.z; a3 += ar * bv.w;
    }
    uint2 pk;
    pk.x = (unsigned)f2bf(a0) | ((unsigned)f2bf(a1) << 16);
    pk.y = (unsigned)f2bf(a2) | ((unsigned)f2bf(a3) << 16);
    *(uint2*)(Wb + (size_t)o * IN_F + i0) = pk;
  }
}

// ---------------------------------------------------------------------------
// GEMM (round-13): r10 base (16 waves, 1024 thr, 2-ahead staging) with
// TRI-BUFFERED B -> ONE barrier per K-tile, provably race-free:
//   tile t reads A[t&1], B[t%3]; stages A(t+1)->A[(t+1)&1] (readers only
//   after bar(t+1)) and B(t+2)->B[(t+2)%3] (readers two barriers away).
// No timing-margin arguments (r9's mistake); safety = buffer disjointness +
// barrier + counted vmcnt only.
// LDS: A 2x32KB + B 3x32KB = 160 KB (full CU LDS; occupancy already 1
// block/CU so nothing lost). Registers unchanged from r10 (64 VGPR + 64
// AGPR = the hard 128 cap for 16-wave blocks).
// Ledger: at bar(t) outstanding = B(t+1)x2; tile stages A(t+1)x2 + B(t+2)x2
// -> 6; WAIT2 at tile end drains B(t+1)+A(t+1), leaves B(t+2). Prologue:
// B(0)x2, A(0)x2, B(1)x2, WAIT2. Tile 62 stages A(63) only, WAIT0. Period-6
// unroll (lcm(2,3)).

#define ABASE(ab) ((ab) * 16384)
#define BBASE(j)  (32768 + (j) * 16384)

#define STAGE_A2(ab, kt) do { \
  gload_lds16(aG + (size_t)(kt),                lds + ABASE(ab) + tid * 8); \
  gload_lds16(aG + (size_t)128 * IN_F + (kt),   lds + ABASE(ab) + 8192 + tid * 8); \
} while (0)

#define STAGE_B2(j, kt) do { \
  gload_lds16(bG + (size_t)(kt),                lds + BBASE(j) + tid * 8); \
  gload_lds16(bG + (size_t)128 * IN_F + (kt),   lds + BBASE(j) + 8192 + tid * 8); \
} while (0)

#define WAIT2 asm volatile("s_waitcnt vmcnt(2)" ::: "memory")
#define WAIT0 asm volatile("s_waitcnt vmcnt(0)" ::: "memory")

#define MFMA16 __builtin_amdgcn_mfma_f32_16x16x32_bf16

// One K-tile: single barrier; slice0 reads; early staging; 2x16 MFMA.
#define KTILE(ab, bj, STAGE_STMT, WAIT_STMT) do { \
  __builtin_amdgcn_s_barrier(); \
  __builtin_amdgcn_sched_barrier(0); \
  _Pragma("unroll") \
  for (int n = 0; n < 4; ++n) \
    Bf[n] = *(const bf16x8*)(lds + BBASE(bj) + (rB + n * 16) * 64 + ck0); \
  _Pragma("unroll") \
  for (int m = 0; m < 4; ++m) \
    Af[m] = *(const bf16x8*)(lds + ABASE(ab) + (rA + m * 16) * 64 + ck0); \
  STAGE_STMT; \
  __builtin_amdgcn_s_setprio(1); \
  _Pragma("unroll") \
  for (int m = 0; m < 4; ++m) \
    _Pragma("unroll") \
    for (int n = 0; n < 4; ++n) \
      acc[m][n] = MFMA16(Af[m], Bf[n], acc[m][n], 0, 0, 0); \
  __builtin_amdgcn_s_setprio(0); \
  _Pragma("unroll") \
  for (int n = 0; n < 4; ++n) \
    Bf[n] = *(const bf16x8*)(lds + BBASE(bj) + (rB + n * 16) * 64 + ck1); \
  _Pragma("unroll") \
  for (int m = 0; m < 4; ++m) \
    Af[m] = *(const bf16x8*)(lds + ABASE(ab) + (rA + m * 16) * 64 + ck1); \
  __builtin_amdgcn_s_setprio(1); \
  _Pragma("unroll") \
  for (int m = 0; m < 4; ++m) \
    _Pragma("unroll") \
    for (int n = 0; n < 4; ++n) \
      acc[m][n] = MFMA16(Af[m], Bf[n], acc[m][n], 0, 0, 0); \
  __builtin_amdgcn_s_setprio(0); \
  WAIT_STMT; \
} while (0)

__global__ __launch_bounds__(1024, 4) void gemm8(const u16* __restrict__ Xb,
                                                 const u16* __restrict__ Wb,
                                                 const float* __restrict__ bias,
                                                 float* __restrict__ out) {
  extern __shared__ u16 lds[];

  const int tid  = threadIdx.x;
  const int lane = tid & 63;
  const int wid  = tid >> 6;                   // 0..15
  const int wr = wid >> 2, wc = wid & 3;       // 4x4 waves, 64x64 C each
  const int lr = lane & 15, kg = lane >> 4;

  // XCD-aware swizzle: nwg = 512, divisible by 8
  const int bid = blockIdx.x;
  const int swz = (bid & 7) * 64 + (bid >> 3);
  const int mt = swz >> 4, nt = swz & 15;       // 32 M-tiles x 16 N-tiles
  const int m0 = mt * 256, n0 = nt * 256;

  // staging: LDS dest linear; global source pre-swizzled chunk^(row&7).
  // 1024 threads: srow 0..127; each stage call covers 128 rows x 64 bf16.
  const int srow = tid >> 3;
  const int swc  = (tid & 7) ^ (srow & 7);
  const u16* aG = Xb + (size_t)(m0 + srow) * IN_F + swc * 8;
  const u16* bG = Wb + (size_t)(n0 + srow) * IN_F + swc * 8;

  // fragment read offsets (proven 0-conflict 16x16 pattern)
  const int rA = wr * 64 + lr;
  const int rB = wc * 64 + lr;
  const int ck0 = ((kg) ^ (lane & 7)) * 8;       // k-slice 0
  const int ck1 = ((4 + kg) ^ (lane & 7)) * 8;   // k-slice 1

  f32x4 acc[4][4] = {};
  bf16x8 Af[4], Bf[4];

  // prologue: B(0), A(0), B(1); WAIT2 -> B0+A0 landed, B1 in flight
  STAGE_B2(0, 0);
  STAGE_A2(0, 0);
  STAGE_B2(1, 64);
  WAIT2;

  // tiles 0..59 in 10 groups of 6 (A period 2, B period 3)
  for (int g = 0; g < 10; ++g) {
    const int k0 = g * 384;
    KTILE(0, 0, STAGE_A2(1, k0 + 64);  STAGE_B2(2, k0 + 128), WAIT2);
    KTILE(1, 1, STAGE_A2(0, k0 + 128); STAGE_B2(0, k0 + 192), WAIT2);
    KTILE(0, 2, STAGE_A2(1, k0 + 192); STAGE_B2(1, k0 + 256), WAIT2);
    KTILE(1, 0, STAGE_A2(0, k0 + 256); STAGE_B2(2, k0 + 320), WAIT2);
    KTILE(0, 1, STAGE_A2(1, k0 + 320); STAGE_B2(0, k0 + 384), WAIT2);
    KTILE(1, 2, STAGE_A2(0, k0 + 384); STAGE_B2(1, k0 + 448), WAIT2);
  }
  // tiles 60..63 (kt = 3840, 3904, 3968, 4032)
  KTILE(0, 0, STAGE_A2(1, 3904); STAGE_B2(2, 3968), WAIT2);
  KTILE(1, 1, STAGE_A2(0, 3968); STAGE_B2(0, 4032), WAIT2);
  KTILE(0, 2, STAGE_A2(1, 4032), WAIT0);
  KTILE(1, 0, , );

  // C write + bias (nontemporal). C/D layout: col = lane&15, row = kg*4 + reg
  float bv[4];
#pragma unroll
  for (int n = 0; n < 4; ++n) bv[n] = bias[n0 + wc * 64 + n * 16 + lr];
  const int rbase = m0 + wr * 64 + kg * 4;
#pragma unroll
  for (int m = 0; m < 4; ++m)
#pragma unroll
    for (int n = 0; n < 4; ++n) {
      int col = n0 + wc * 64 + n * 16 + lr;
#pragma unroll
      for (int r = 0; r < 4; ++r)
        __builtin_nontemporal_store(acc[m][n][r] + bv[n],
                                    &out[(size_t)(rbase + m * 16 + r) * OUT_F + col]);
    }
}

// ---------------------------------------------------------------------------
// Fallback GEMM (proven round-1 kernel): 128x128 tile, m97 structure, 859 TF.
__global__ __launch_bounds__(256) void gemm_bias(const u16* __restrict__ Xb,
                                                 const u16* __restrict__ Wb,
                                                 const float* __restrict__ bias,
                                                 float* __restrict__ out) {
  __shared__ __align__(16) u16 ldsA[128 * 64];
  __shared__ __align__(16) u16 ldsB[128 * 64];

  const int tid  = threadIdx.x;
  const int wid  = tid >> 6;
  const int lane = tid & 63;
  const int nt = blockIdx.x & 31;
  const int mt = blockIdx.x >> 5;
  const int m0 = mt * 128, n0 = nt * 128;
  const int wr = wid >> 1, wc = wid & 1;
  const int lr = lane & 15;
  const int kg = lane >> 4;

  const int srow   = wid * 8 + (lane >> 3);
  const int schunk = (lane & 7) ^ (srow & 7);
  const u16* aSrc = Xb + (size_t)(m0 + srow) * IN_F + schunk * 8;
  const u16* bSrc = Wb + (size_t)(n0 + srow) * IN_F + schunk * 8;

  f32x4 acc[4][4] = {};

  for (int kt = 0; kt < IN_F; kt += 64) {
    __syncthreads();
#pragma unroll
    for (int j = 0; j < 4; ++j) {
      gload_lds16(aSrc + (size_t)(j * 32) * IN_F + kt, &ldsA[j * 2048 + wid * 512]);
      gload_lds16(bSrc + (size_t)(j * 32) * IN_F + kt, &ldsB[j * 2048 + wid * 512]);
    }
    __syncthreads();

#pragma unroll
    for (int s = 0; s < 2; ++s) {
      bf16x8 af[4], bfr[4];
#pragma unroll
      for (int m = 0; m < 4; ++m) {
        int r = wr * 64 + m * 16 + lr;
        int c = (s * 4 + kg) ^ (r & 7);
        af[m] = *(const bf16x8*)&ldsA[r * 64 + c * 8];
      }
#pragma unroll
      for (int n = 0; n < 4; ++n) {
        int r = wc * 64 + n * 16 + lr;
        int c = (s * 4 + kg) ^ (r & 7);
        bfr[n] = *(const bf16x8*)&ldsB[r * 64 + c * 8];
      }
#pragma unroll
      for (int m = 0; m < 4; ++m)
#pragma unroll
        for (int n = 0; n < 4; ++n)
          acc[m][n] = __builtin_amdgcn_mfma_f32_16x16x32_bf16(af[m], bfr[n], acc[m][n], 0, 0, 0);
    }
  }

  float bv[4];
#pragma unroll
  for (int n = 0; n < 4; ++n) bv[n] = bias[n0 + wc * 64 + n * 16 + lr];
  const int rbase = m0 + wr * 64 + kg * 4;
#pragma unroll
  for (int m = 0; m < 4; ++m)
#pragma unroll
    for (int n = 0; n < 4; ++n) {
      int col = n0 + wc * 64 + n * 16 + lr;
#pragma unroll
      for (int r = 0; r < 4; ++r)
        out[(size_t)(rbase + m * 16 + r) * OUT_F + col] = acc[m][n][r] + bv[n];
    }
}

// ---------------------------------------------------------------------------
// fp32 fallback (tiny workspace): exact, slow but correct.
__global__ void lora_t(const float* __restrict__ x, const float* __restrict__ B,
                       float* __restrict__ t) {
  int m = blockIdx.x;
  int tid = threadIdx.x, lane = tid & 63;
  float p[8] = {0, 0, 0, 0, 0, 0, 0, 0};
  for (int k = tid; k < IN_F; k += 256) {
    float xv = x[(size_t)m * IN_F + k];
#pragma unroll
    for (int r = 0; r < 8; ++r) p[r] += xv * B[r * IN_F + k];
  }
#pragma unroll
  for (int r = 0; r < 8; ++r) {
    float v = p[r];
    for (int off = 32; off; off >>= 1) v += __shfl_down(v, off);
    if (lane == 0) atomicAdd(&t[m * 8 + r], v);
  }
}

__global__ void fb_gemm(const float* __restrict__ x, const float* __restrict__ W,
                        const float* __restrict__ A, const float* __restrict__ bias,
                        const float* __restrict__ t, float* __restrict__ out) {
  __shared__ float sx[64][17];
  __shared__ float sw[64][17];
  int tx = threadIdx.x, ty = threadIdx.y;
  int tid = ty * 16 + tx;
  int m0 = blockIdx.y * 64, n0 = blockIdx.x * 64;
  float acc[4][4] = {};
  for (int kt = 0; kt < IN_F; kt += 16) {
    __syncthreads();
#pragma unroll
    for (int q = 0; q < 4; ++q) {
      int idx = q * 256 + tid;
      int r = idx >> 4, c = idx & 15;
      sx[r][c] = x[(size_t)(m0 + r) * IN_F + kt + c];
      sw[r][c] = W[(size_t)(n0 + r) * IN_F + kt + c];
    }
    __syncthreads();
#pragma unroll
    for (int k = 0; k < 16; ++k) {
      float xv[4], wv[4];
#pragma unroll
      for (int i = 0; i < 4; ++i) xv[i] = sx[ty * 4 + i][k];
#pragma unroll
      for (int j = 0; j < 4; ++j) wv[j] = sw[tx * 4 + j][k];
#pragma unroll
      for (int i = 0; i < 4; ++i)
#pragma unroll
        for (int j = 0; j < 4; ++j) acc[i][j] += xv[i] * wv[j];
    }
  }
#pragma unroll
  for (int i = 0; i < 4; ++i) {
    int m = m0 + ty * 4 + i;
    float tv[8];
#pragma unroll
    for (int r = 0; r < 8; ++r) tv[r] = t[m * 8 + r];
#pragma unroll
    for (int j = 0; j < 4; ++j) {
      int o = n0 + tx * 4 + j;
      float lora = 0.f;
#pragma unroll
      for (int r = 0; r < 8; ++r) lora += tv[r] * A[o * 8 + r];
      out[(size_t)m * OUT_F + o] = acc[i][j] + bias[o] + LORA_SCALE * lora;
    }
  }
}

// ---------------------------------------------------------------------------
extern "C" void kernel_launch(void* const* d_in, const int* in_sizes, int n_in,
                              void* d_out, int out_size, void* d_ws, size_t ws_size,
                              hipStream_t stream) {
  const float* x    = (const float*)d_in[0];
  const float* W    = (const float*)d_in[1];
  const float* A    = (const float*)d_in[2];
  const float* B    = (const float*)d_in[3];
  const float* bias = (const float*)d_in[4];
  float* out = (float*)d_out;

  const size_t xb_elems = (size_t)M_TOT * IN_F;
  const size_t wb_elems = (size_t)OUT_F * IN_F;

  if (ws_size >= (xb_elems + wb_elems) * sizeof(u16)) {
    u16* Xb = (u16*)d_ws;
    u16* Wb = Xb + xb_elems;
    prep<<<32768, 256, 0, stream>>>(x, W, A, B, Xb, Wb);

    hipError_t e = hipFuncSetAttribute((const void*)gemm8,
                                       hipFuncAttributeMaxDynamicSharedMemorySize,
                                       163840);
    bool used8 = false;
    if (e == hipSuccess) {
      gemm8<<<512, 1024, 163840, stream>>>(Xb, Wb, bias, out);
      used8 = (hipGetLastError() == hipSuccess);
    }
    if (!used8) {
      gemm_bias<<<(M_TOT / 128) * (OUT_F / 128), 256, 0, stream>>>(Xb, Wb, bias, out);
    }
  } else {
    float* t = (float*)d_ws;
    (void)hipMemsetAsync(t, 0, (size_t)M_TOT * 8 * sizeof(float), stream);
    lora_t<<<M_TOT, 256, 0, stream>>>(x, B, t);
    fb_gemm<<<dim3(OUT_F / 64, M_TOT / 64), dim3(16, 16), 0, stream>>>(x, W, A, bias, t, out);
  }
}